// Round 1
// baseline (153.304 us; speedup 1.0000x reference)
//
#include <hip/hip_runtime.h>

// Problem: D=512, H=8, L=4, NE=8, B=32, S=512. fp32 in / fp32 out.
//
// Reduction chain (R3-verified absmax 0.0, R4 3.8e-6):
//   cross-attn Sk=1 -> softmax==1 -> last[b] = (ctx[b]@cWv+cbv)@cWo+cbo,
//   ctx[b] = c0[b]*ctxW[0] + c1[b]*ctxW[1] + ctxb  -> batch factors out:
//     A_i = x_i@cWv (x={ctxW0,ctxW1,ctxb}), A2+=cbv
//     B_i = A_i@cWo, B2+=cbo
//     P_i[s,h] = B_i@spW[h][s], P2+=spb
//     out[b,h,o] = c0[b]*P0 + c1[b]*P1 + P2   (s=sid[b])
//
// Cost model: harness restore+poison floor ~125us (256MB ws poison fill at
// 80% HBM peak — untouchable). Prior rounds: coop launch +70us (R5), naive
// cross-dispatch flag barriers ~= graph gaps (R6), per-block redundant
// compute = per-CU BW trap (R7). R8 (this round): collapse to ONE dispatch:
//   - chain depth 3 -> 2: block e-slice computes A[:,e] AND its rank-16
//     partial of B = A@cWo, atomicAdd into ws (no redundancy, no extra stage)
//   - consumers preload ALL spW weights into regs BEFORE spinning on the
//     producer counter -> every HBM load in the problem is in flight at t=0;
//     the handoff only waits on 6KB of B through the coherence point.
//   - flags/B zeroed by a tiny on-stream hipMemsetAsync (runs after the
//     harness poison) -> no reliance on poison pattern or stale ws.
//   - single-dispatch producer/consumer is safe under rocprof serialized
//     replay (cross-dispatch flags would deadlock there).

#define DD 512

__global__ __launch_bounds__(256) void fused_chain(
    const float* __restrict__ ctxW,   // (2,512)
    const float* __restrict__ ctxb,   // (512)
    const float* __restrict__ cWv,    // (512,512)
    const float* __restrict__ cbv,    // (512)
    const float* __restrict__ cWo,    // (512,512)
    const float* __restrict__ cbo,    // (512)
    const float* __restrict__ spWp, const float* __restrict__ spbp,
    const float* __restrict__ spWa, const float* __restrict__ spba,
    const float* __restrict__ ctxin,  // (32,2)
    const int*   __restrict__ sid,    // (32)
    float*       __restrict__ Bacc,   // ws (3,512)  pre-zeroed
    unsigned*    __restrict__ ctr,    // ws          pre-zeroed
    float*       __restrict__ out)    // pred (32,64) then act (32,64)
{
    const int t   = threadIdx.x;
    const int blk = blockIdx.x;

    if (blk < 32) {
        // ---------- producer: A e-slice + rank-16 partial of B ----------
        __shared__ float sx[3 * DD];
        __shared__ float red[16][48];   // [dgroup][e16*3+vec]
        __shared__ float sA[48];        // [e16*3+vec]
        const int ebase = blk * 16;
        const int e16 = t & 15, dg = t >> 4;   // 16 e-cols x 16 d-groups of 32

        // issue ALL weight loads up front (64 independent loads in flight)
        const float* wv = cWv + (size_t)(dg * 32) * DD + ebase + e16;
        float wregV[32];
        #pragma unroll
        for (int j = 0; j < 32; ++j) wregV[j] = wv[(size_t)j * DD];

        const float* wo = cWo + (size_t)ebase * DD + t;   // rows e-slice, col t
        float wregO0[16], wregO1[16];
        #pragma unroll
        for (int j = 0; j < 16; ++j) {
            wregO0[j] = wo[(size_t)j * DD];
            wregO1[j] = wo[(size_t)j * DD + 256];
        }

        for (int i = t; i < 2 * DD; i += 256) sx[i] = ctxW[i];
        for (int i = t; i < DD; i += 256)     sx[2 * DD + i] = ctxb[i];
        __syncthreads();

        // A[i, ebase+e16] partial over this thread's 32 d's
        float p0 = 0.f, p1 = 0.f, p2 = 0.f;
        #pragma unroll
        for (int j = 0; j < 32; ++j) {
            const int d = dg * 32 + j;
            p0 += sx[d] * wregV[j];
            p1 += sx[DD + d] * wregV[j];
            p2 += sx[2 * DD + d] * wregV[j];
        }
        red[dg][e16 * 3 + 0] = p0;
        red[dg][e16 * 3 + 1] = p1;
        red[dg][e16 * 3 + 2] = p2;
        __syncthreads();

        if (t < 48) {                          // t = e16*3+vec
            float s = 0.f;
            #pragma unroll
            for (int g = 0; g < 16; ++g) s += red[g][t];
            if (t % 3 == 2) s += cbv[ebase + t / 3];
            sA[t] = s;
        }
        __syncthreads();

        // partial B[i, c] for c=t and c=t+256 over this block's 16 e's
        float b0a = 0.f, b1a = 0.f, b2a = 0.f;
        float b0b = 0.f, b1b = 0.f, b2b = 0.f;
        #pragma unroll
        for (int j = 0; j < 16; ++j) {
            const float a0 = sA[j * 3 + 0];
            const float a1 = sA[j * 3 + 1];
            const float a2 = sA[j * 3 + 2];
            b0a += a0 * wregO0[j];  b1a += a1 * wregO0[j];  b2a += a2 * wregO0[j];
            b0b += a0 * wregO1[j];  b1b += a1 * wregO1[j];  b2b += a2 * wregO1[j];
        }
        atomicAdd(&Bacc[0 * DD + t],       b0a);
        atomicAdd(&Bacc[1 * DD + t],       b1a);
        atomicAdd(&Bacc[2 * DD + t],       b2a);
        atomicAdd(&Bacc[0 * DD + t + 256], b0b);
        atomicAdd(&Bacc[1 * DD + t + 256], b1b);
        atomicAdd(&Bacc[2 * DD + t + 256], b2b);
        __syncthreads();   // barrier drains every wave's outstanding vmem
        if (t == 0) {
            __threadfence();
            __hip_atomic_fetch_add(ctr, 1u, __ATOMIC_RELEASE,
                                   __HIP_MEMORY_SCOPE_AGENT);
        }
    } else {
        // ---------- consumer: heads + batch broadcast ----------
        __shared__ float sb[3 * DD];
        __shared__ float red[16][48];   // [dgroup][o16*3+vec]
        __shared__ float pv[48];
        __shared__ float sc0[32], sc1[32];
        __shared__ int   ssid[32];
        const int bb = blk - 32;
        const int s = bb & 7, h = (bb >> 3) & 1, q = bb >> 4;

        // issue ALL weight loads BEFORE spinning (latency overlaps producer)
        const float* W    = (h ? spWa : spWp) + (size_t)s * DD * 64;
        const float* bias = (h ? spba : spbp) + s * 64;
        const int o16 = t & 15, dg = t >> 4;   // 16 outs x 16 d-groups of 32
        const float* wp = W + (size_t)(dg * 32) * 64 + q * 16 + o16;
        float wreg[32];
        #pragma unroll
        for (int j = 0; j < 32; ++j) wreg[j] = wp[(size_t)j * 64];

        if (t < 32) {
            ssid[t] = sid[t];
            sc0[t] = ctxin[2 * t];
            sc1[t] = ctxin[2 * t + 1];
        }

        // one wave spins on the producer counter (bounded: fail visibly,
        // never hang)
        if (t < 64) {
            for (int it = 0; it < (1 << 22); ++it) {
                if (__hip_atomic_load(ctr, __ATOMIC_RELAXED,
                                      __HIP_MEMORY_SCOPE_AGENT) == 32u)
                    break;
            }
            __threadfence();   // acquire side: invalidate stale cache lines
        }
        __syncthreads();

        // B is tiny (6KB): read through the coherence point; fold cbo in
        for (int i = t; i < 2 * DD; i += 256)
            sb[i] = __hip_atomic_load(&Bacc[i], __ATOMIC_RELAXED,
                                      __HIP_MEMORY_SCOPE_AGENT);
        for (int i = t; i < DD; i += 256)
            sb[2 * DD + i] = __hip_atomic_load(&Bacc[2 * DD + i],
                                               __ATOMIC_RELAXED,
                                               __HIP_MEMORY_SCOPE_AGENT)
                             + cbo[i];
        __syncthreads();

        float p0 = 0.f, p1 = 0.f, p2 = 0.f;
        #pragma unroll
        for (int j = 0; j < 32; ++j) {
            const int d = dg * 32 + j;
            p0 += sb[d] * wreg[j];
            p1 += sb[DD + d] * wreg[j];
            p2 += sb[2 * DD + d] * wreg[j];
        }
        red[dg][o16 * 3 + 0] = p0;
        red[dg][o16 * 3 + 1] = p1;
        red[dg][o16 * 3 + 2] = p2;
        __syncthreads();

        if (t < 48) {                          // t = oo*3+vec
            float a = 0.f;
            #pragma unroll
            for (int g = 0; g < 16; ++g) a += red[g][t];
            if (t % 3 == 2) a += bias[q * 16 + t / 3];
            pv[t] = a;
        }
        __syncthreads();

        if (t < 16) {
            const float v0 = pv[t * 3], v1 = pv[t * 3 + 1], v2 = pv[t * 3 + 2];
            #pragma unroll
            for (int b = 0; b < 32; ++b) {
                if (ssid[b] == s) {            // wave-uniform
                    out[h * 2048 + b * 64 + q * 16 + t] =
                        sc0[b] * v0 + sc1[b] * v1 + v2;
                }
            }
        }
    }
}

extern "C" void kernel_launch(void* const* d_in, const int* in_sizes, int n_in,
                              void* d_out, int out_size, void* d_ws, size_t ws_size,
                              hipStream_t stream) {
    // 0 x_batch, 1 context_batch, 2 specialist_ids, 3 emb, 4-11 attn, 12-15 ln,
    // 16-19 ffn, 20 ctxW, 21 ctxb, 22-25 cWq/cWk, 26 cWv, 27 cbv, 28 cWo,
    // 29 cbo, 30 spWp, 31 spbp, 32 spWa, 33 spba
    const float* ctxin = (const float*)d_in[1];
    const int*   sid   = (const int*)d_in[2];
    const float* ctxW  = (const float*)d_in[20];
    const float* ctxb  = (const float*)d_in[21];
    const float* cWv   = (const float*)d_in[26];
    const float* cbv   = (const float*)d_in[27];
    const float* cWo   = (const float*)d_in[28];
    const float* cbo   = (const float*)d_in[29];
    const float* spWp  = (const float*)d_in[30];
    const float* spbp  = (const float*)d_in[31];
    const float* spWa  = (const float*)d_in[32];
    const float* spba  = (const float*)d_in[33];
    float*    out  = (float*)d_out;
    float*    Bacc = (float*)d_ws;                       // (3,512) fp32
    unsigned* ctr  = (unsigned*)((char*)d_ws + 3 * DD * sizeof(float));

    // zero the accumulator + counter AFTER the harness poison, every replay
    hipMemsetAsync(d_ws, 0, 3 * DD * sizeof(float) + 64, stream);

    fused_chain<<<dim3(96), dim3(256), 0, stream>>>(
        ctxW, ctxb, cWv, cbv, cWo, cbo,
        spWp, spbp, spWa, spba, ctxin, sid, Bacc, ctr, out);
}